// Round 8
// baseline (426.246 us; speedup 1.0000x reference)
//
#include <hip/hip_runtime.h>
#include <hip/hip_bf16.h>
#include <cstdint>

#define P_ 88   // pitches (sequence length of the scan)
#define B_ 16   // batch
#define T_ 256  // timesteps (folded into batch N)
#define H_ 188  // per-pitch features
#define G_ 192  // 4*48 gates; also LSTM1 input size (188 feat + 4 ctx)
#define U_ 48   // LSTM units
#define N_ 4096 // B_*T_

typedef __attribute__((ext_vector_type(8))) short bf16x8;
typedef __attribute__((ext_vector_type(8))) _Float16 f16x8;
typedef __attribute__((ext_vector_type(4))) float f32x4;

__device__ __forceinline__ float sigf(float x) {
  return __builtin_amdgcn_rcpf(1.0f + __expf(-x));
}
__device__ __forceinline__ float tanh_f(float x) {
  return 1.0f - 2.0f * __builtin_amdgcn_rcpf(1.0f + __expf(2.0f * x));
}
__device__ __forceinline__ unsigned short f2bs(float v) {
  union { __hip_bfloat16 h; unsigned short s; } u;
  u.h = __float2bfloat16(v);
  return u.s;
}
__device__ __forceinline__ float bs2f(unsigned short s) {
  union { unsigned int u; float f; } x;
  x.u = ((unsigned int)s) << 16;
  return x.f;
}
__device__ __forceinline__ float hs2f(unsigned short s) {
  union { unsigned short u; _Float16 h; } x;
  x.u = s;
  return (float)x.h;
}
__device__ __forceinline__ unsigned short f2hs(float v) {
  union { _Float16 h; unsigned short s; } x;
  x.h = (_Float16)v;
  return x.s;
}

// ---------------------------------------------------------------------------
// Kernel 1: context MLP -> per-(b,p) gate bias vector
// ---------------------------------------------------------------------------
__global__ void ctx_kernel(const float* __restrict__ pc,
                           const float* __restrict__ fc1w, const float* __restrict__ fc1b,
                           const float* __restrict__ fc2w, const float* __restrict__ fc2b,
                           const float* __restrict__ fc3w, const float* __restrict__ fc3b,
                           const float* __restrict__ wih1,
                           const float* __restrict__ bih1, const float* __restrict__ bhh1,
                           float* __restrict__ ctxg) {
  int bp = blockIdx.x * 64 + threadIdx.x;
  if (bp >= B_ * P_) return;
  float p0 = pc[bp * 3 + 0], p1 = pc[bp * 3 + 1], p2 = pc[bp * 3 + 2];
  float x1[16], x2[16];
#pragma unroll
  for (int jj = 0; jj < 16; ++jj)
    x1[jj] = fmaxf(0.f, fc1w[jj * 3 + 0] * p0 + fc1w[jj * 3 + 1] * p1 + fc1w[jj * 3 + 2] * p2 + fc1b[jj]);
#pragma unroll
  for (int jj = 0; jj < 16; ++jj) {
    float s = fc2b[jj];
#pragma unroll
    for (int i = 0; i < 16; ++i) s += fc2w[jj * 16 + i] * x1[i];
    x2[jj] = fmaxf(0.f, s);
  }
  float ce[4];
#pragma unroll
  for (int jj = 0; jj < 4; ++jj) {
    float s = fc3b[jj];
#pragma unroll
    for (int i = 0; i < 16; ++i) s += fc3w[jj * 16 + i] * x2[i];
    ce[jj] = s;
  }
  float* op = ctxg + (size_t)bp * G_;
  for (int g = 0; g < G_; ++g) {
    const float* wr = wih1 + (size_t)g * G_ + H_;
    op[g] = bih1[g] + bhh1[g] + ce[0] * wr[0] + ce[1] * wr[1] + ce[2] * wr[2] + ce[3] * wr[3];
  }
}

// ---------------------------------------------------------------------------
// Kernel 1b: pack wih1 feature columns (k<188, pad to 192) into f16 MFMA
// B-fragment order: wfrag[(j*6+kc)*64 + l] (74 KB, L2-hot for all blocks).
// ---------------------------------------------------------------------------
__global__ __launch_bounds__(256) void wfrag_kernel(const float* __restrict__ wih1,
                                                    f16x8* __restrict__ wfrag) {
  const int idx = blockIdx.x * 256 + threadIdx.x;
  if (idx >= 12 * 6 * 64) return;
  const int l = idx & 63;
  const int kc = (idx >> 6) % 6;
  const int j = idx / 384;
  const int g = j * 16 + (l & 15);
  const int k0 = kc * 32 + (l >> 4) * 8;
  f16x8 v;
#pragma unroll
  for (int e = 0; e < 8; ++e) {
    const int k = k0 + e;
    const float wv = (k < H_) ? wih1[(size_t)g * G_ + k] : 0.f;
    v[e] = (_Float16)wv;
  }
  wfrag[idx] = v;
}

// ---------------------------------------------------------------------------
// Kernel 2: MFMA GEMM with LDS-staged A and LDS-repacked stores (unchanged).
// ---------------------------------------------------------------------------
__global__ __launch_bounds__(256, 3) void gemm_mfma(const float* __restrict__ pf,
                                                    const f16x8* __restrict__ wfrag,
                                                    const float* __restrict__ ctxg,
                                                    unsigned short* __restrict__ xg2) {
  const int bp = blockIdx.x >> 1, tb = blockIdx.x & 1;
  const int p = bp % P_, b = bp / P_;
  const int tid = threadIdx.x;
  const int w = tid >> 6, l = tid & 63;
  const int lj = l & 15, lq = l >> 4;

  __shared__ __align__(16) char ldsraw[49152];  // 48 KB: staging then epilogue
  _Float16(*Ahi)[34] = (_Float16(*)[34])ldsraw;             // [128][34] f16
  _Float16(*Alo)[34] = (_Float16(*)[34])(ldsraw + 8704);    // [128][34] f16

  float cg[12];
#pragma unroll
  for (int jn = 0; jn < 12; ++jn)
    cg[jn] = ctxg[(size_t)bp * G_ + jn * 16 + lj];

  f32x4 acc[2][12];
#pragma unroll
  for (int mt = 0; mt < 2; ++mt)
#pragma unroll
    for (int jn = 0; jn < 12; ++jn)
#pragma unroll
      for (int r = 0; r < 4; ++r) acc[mt][jn][r] = 0.f;

  const float* Ab = pf + (size_t)bp * H_ * T_ + tb * 128;
  const int kl = tid >> 5;         // 0..7  (k row within an 8-row group)
  const int t4 = (tid & 31) * 4;   // 0..124 (t within the 128-half)

  for (int kc = 0; kc < 6; ++kc) {
    __syncthreads();  // previous chunk's fragment reads complete
#pragma unroll
    for (int rr = 0; rr < 4; ++rr) {
      const int kk = rr * 8 + kl;       // 0..31 within chunk
      const int kg = kc * 32 + kk;
      float a0 = 0.f, a1 = 0.f, a2 = 0.f, a3 = 0.f;
      if (kg < H_) {
        const float4 v = *(const float4*)(Ab + (size_t)kg * T_ + t4);
        a0 = v.x; a1 = v.y; a2 = v.z; a3 = v.w;
      }
      const _Float16 h0 = (_Float16)a0, h1 = (_Float16)a1;
      const _Float16 h2 = (_Float16)a2, h3 = (_Float16)a3;
      Ahi[t4 + 0][kk] = h0; Alo[t4 + 0][kk] = (_Float16)(a0 - (float)h0);
      Ahi[t4 + 1][kk] = h1; Alo[t4 + 1][kk] = (_Float16)(a1 - (float)h1);
      Ahi[t4 + 2][kk] = h2; Alo[t4 + 2][kk] = (_Float16)(a2 - (float)h2);
      Ahi[t4 + 3][kk] = h3; Alo[t4 + 3][kk] = (_Float16)(a3 - (float)h3);
    }
    __syncthreads();
    const int trow = w * 32;
    const f16x8 ahi0 = *(const f16x8*)&Ahi[trow + lj][lq * 8];
    const f16x8 ahi1 = *(const f16x8*)&Ahi[trow + 16 + lj][lq * 8];
    const f16x8 alo0 = *(const f16x8*)&Alo[trow + lj][lq * 8];
    const f16x8 alo1 = *(const f16x8*)&Alo[trow + 16 + lj][lq * 8];
#pragma unroll
    for (int jn = 0; jn < 12; ++jn) {
      const f16x8 wf = wfrag[(jn * 6 + kc) * 64 + l];
      acc[0][jn] = __builtin_amdgcn_mfma_f32_16x16x32_f16(ahi0, wf, acc[0][jn], 0, 0, 0);
      acc[1][jn] = __builtin_amdgcn_mfma_f32_16x16x32_f16(ahi1, wf, acc[1][jn], 0, 0, 0);
      acc[0][jn] = __builtin_amdgcn_mfma_f32_16x16x32_f16(alo0, wf, acc[0][jn], 0, 0, 0);
      acc[1][jn] = __builtin_amdgcn_mfma_f32_16x16x32_f16(alo1, wf, acc[1][jn], 0, 0, 0);
    }
  }
  __syncthreads();  // staging region now free for epilogue reuse

  // ---- epilogue: + ctx bias, f16, repack via per-wave LDS, uint4 stores ----
  unsigned short* Cst = (unsigned short*)ldsraw + w * 6144;  // 12 KB per wave
#pragma unroll
  for (int mt = 0; mt < 2; ++mt)
#pragma unroll
    for (int jn = 0; jn < 12; ++jn)
#pragma unroll
      for (int r = 0; r < 4; ++r)
        Cst[mt * 3072 + jn * 256 + r * 64 + l] = f2hs(acc[mt][jn][r] + cg[jn]);
  const int nb0 = b * 16 + tb * 8 + w * 2;
  unsigned short* gb = xg2 + ((size_t)p * 256 + nb0) * 3072;
#pragma unroll
  for (int rr = 0; rr < 12; ++rr) {
    const uint4 v = *(const uint4*)(Cst + rr * 512 + l * 8);
    *(uint4*)(gb + rr * 512 + l * 8) = v;
  }
}

// ---------------------------------------------------------------------------
// Kernel 3: MFMA persistent scan. NB=8 rows/block, 512 blocks = 2 blocks/CU
// (round-7 was 256 blocks = 1/CU, latency-bound at 11% occupancy).
// A rows 8-15 zero; C rows 8-15 ignored. xg2 half-group read: stored quad
// q = half*2+lq for lanes lq<2, zeros elsewhere.
// ---------------------------------------------------------------------------
__global__ __launch_bounds__(256, 2) void scan_mfma(
    const unsigned short* __restrict__ xg2,
    const float* __restrict__ whh1, const float* __restrict__ wih2,
    const float* __restrict__ whh2, const float* __restrict__ bih2,
    const float* __restrict__ bhh2, const float* __restrict__ fcw,
    const float* __restrict__ fcb, float* __restrict__ out) {
  __shared__ __align__(16) short hh[16][104];   // h hi bits: cols 0-47 h1, 48-95 h2 (rows 8-15 stay 0)
  __shared__ __align__(16) short hl[16][104];   // h lo bits
  __shared__ __align__(16) float gs[8][196];    // gate staging (one layer at a time)
  __shared__ __align__(16) float h2f[8][52];    // h2 fp32 for fc_states
  __shared__ __align__(16) float fcws[5 * 48];
  __shared__ float logit_s[5][8];
  __shared__ float prob_s[5][8];

  const int tid = threadIdx.x;
  const int w = tid >> 6;   // wave 0..3
  const int l = tid & 63;
  const int lj = l & 15;    // A-row m / C col n within a 16-tile
  const int lq = l >> 4;    // quad
  const int grp = blockIdx.x >> 1;   // 16-row group in xg2
  const int half = blockIdx.x & 1;   // which 8-row half
  const int n0 = blockIdx.x * 8;
  const int b = n0 >> 8, t0 = n0 & 255;

  // ---- persistent weight B-fragments (one-time gather) ----
  bf16x8 b1[3][2];
  bf16x8 b2f[3][3];
  float bias2r[3];
#pragma unroll
  for (int i = 0; i < 3; ++i) {
    const int j = w * 48 + i * 16 + lj;
    bias2r[i] = bih2[j] + bhh2[j];
#pragma unroll
    for (int kc = 0; kc < 2; ++kc)
#pragma unroll
      for (int e = 0; e < 8; ++e) {
        const int u = kc * 32 + lq * 8 + e;
        b1[i][kc][e] = (u < U_) ? (short)f2bs(whh1[j * U_ + u]) : (short)0;
      }
#pragma unroll
    for (int kc = 0; kc < 3; ++kc)
#pragma unroll
      for (int e = 0; e < 8; ++e) {
        const int u = kc * 32 + lq * 8 + e;
        b2f[i][kc][e] = (u < U_) ? (short)f2bs(wih2[j * U_ + u])
                                 : (short)f2bs(whh2[j * U_ + (u - U_)]);
      }
  }

  for (int e = tid; e < 16 * 104 / 2; e += 256) {
    ((unsigned int*)hh)[e] = 0u;
    ((unsigned int*)hl)[e] = 0u;
  }
  for (int e = tid; e < 5 * U_; e += 256) fcws[e] = fcw[e];

  // activation tasks: 8 rows x 48 units = 384 per layer; slot 0 = tid,
  // slot 1 = 256+tid (valid for tid<128)
  const int tn0 = tid / U_, tu0 = tid % U_;
  const int tn1 = (256 + tid) / U_, tu1 = (256 + tid) % U_;
  float c1r[2] = {0.f, 0.f}, c2r[2] = {0.f, 0.f};
  // fc-logit threads (0..39), softmax threads (192..199), store threads (96..135)
  const bool fcth = tid < 40;
  const int fk = tid >> 3, fn = tid & 7;
  const float fcbr = fcth ? fcb[fk] : 0.f;
  const int sk = (tid - 96) >> 3, sn = (tid - 96) & 7;

  // xg prefetch for p=0 (lanes lq<2 hold rows half*8 + lq*4+r)
  unsigned short xp[12];
  {
    const size_t pb = (size_t)grp * 3072;
#pragma unroll
    for (int i = 0; i < 3; ++i)
#pragma unroll
      for (int r = 0; r < 4; ++r)
        xp[i * 4 + r] = (lq < 2)
            ? xg2[pb + (size_t)((w * 3 + i) * 256 + r * 64 + (half * 2 + lq) * 16 + lj)]
            : (unsigned short)0;
  }
  const short* hhrow = &hh[lj][0];
  const short* hlrow = &hl[lj][0];
  __syncthreads();

  for (int p = 0; p < P_; ++p) {
    // ---- PHASE A: L1 MFMA (C init = xg) | fc_states logits for p-1 ----
    f32x4 c1f[3];
#pragma unroll
    for (int i = 0; i < 3; ++i)
#pragma unroll
      for (int r = 0; r < 4; ++r) c1f[i][r] = hs2f(xp[i * 4 + r]);
    {
      bf16x8 ah0 = *(const bf16x8*)(hhrow + lq * 8);
      bf16x8 ah1 = *(const bf16x8*)(hhrow + 32 + lq * 8);
      bf16x8 al0 = *(const bf16x8*)(hlrow + lq * 8);
      bf16x8 al1 = *(const bf16x8*)(hlrow + 32 + lq * 8);
#pragma unroll
      for (int i = 0; i < 3; ++i)
        c1f[i] = __builtin_amdgcn_mfma_f32_16x16x32_bf16(ah0, b1[i][0], c1f[i], 0, 0, 0);
#pragma unroll
      for (int i = 0; i < 3; ++i)
        c1f[i] = __builtin_amdgcn_mfma_f32_16x16x32_bf16(ah1, b1[i][1], c1f[i], 0, 0, 0);
#pragma unroll
      for (int i = 0; i < 3; ++i)
        c1f[i] = __builtin_amdgcn_mfma_f32_16x16x32_bf16(al0, b1[i][0], c1f[i], 0, 0, 0);
#pragma unroll
      for (int i = 0; i < 3; ++i)
        c1f[i] = __builtin_amdgcn_mfma_f32_16x16x32_bf16(al1, b1[i][1], c1f[i], 0, 0, 0);
    }
    if (lq < 2) {
#pragma unroll
      for (int i = 0; i < 3; ++i)
#pragma unroll
        for (int r = 0; r < 4; ++r)
          gs[lq * 4 + r][w * 48 + i * 16 + lj] = c1f[i][r];
    }
    if (p > 0 && fcth) {
      float a = fcbr;
#pragma unroll
      for (int uq = 0; uq < 12; ++uq) {
        f32x4 hv = *(const f32x4*)&h2f[fn][uq * 4];
        f32x4 wv = *(const f32x4*)&fcws[fk * 48 + uq * 4];
        a += hv[0] * wv[0] + hv[1] * wv[1] + hv[2] * wv[2] + hv[3] * wv[3];
      }
      logit_s[fk][fn] = a;
    }
    __syncthreads();
    // ---- PHASE B: L1 activations/h1 update | softmax for p-1 ----
    {
      const int n = tn0, u = tu0;
      const float ig = gs[n][u], fg = gs[n][48 + u];
      const float gg = gs[n][96 + u], og = gs[n][144 + u];
      const float cc = sigf(fg) * c1r[0] + sigf(ig) * tanh_f(gg);
      c1r[0] = cc;
      const float h = sigf(og) * tanh_f(cc);
      const unsigned short hb = f2bs(h);
      hh[n][u] = (short)hb;
      hl[n][u] = (short)f2bs(h - bs2f(hb));
    }
    if (tid < 128) {
      const int n = tn1, u = tu1;
      const float ig = gs[n][u], fg = gs[n][48 + u];
      const float gg = gs[n][96 + u], og = gs[n][144 + u];
      const float cc = sigf(fg) * c1r[1] + sigf(ig) * tanh_f(gg);
      c1r[1] = cc;
      const float h = sigf(og) * tanh_f(cc);
      const unsigned short hb = f2bs(h);
      hh[n][u] = (short)hb;
      hl[n][u] = (short)f2bs(h - bs2f(hb));
    }
    if (p > 0 && tid >= 192 && tid < 200) {
      const int n = tid - 192;
      const float l0 = logit_s[0][n], l1 = logit_s[1][n], l2 = logit_s[2][n],
                  l3 = logit_s[3][n], l4 = logit_s[4][n];
      const float m = fmaxf(fmaxf(fmaxf(l0, l1), fmaxf(l2, l3)), l4);
      const float e0 = __expf(l0 - m), e1 = __expf(l1 - m), e2 = __expf(l2 - m),
                  e3 = __expf(l3 - m), e4 = __expf(l4 - m);
      const float rs = __builtin_amdgcn_rcpf(e0 + e1 + e2 + e3 + e4);
      prob_s[0][n] = e0 * rs; prob_s[1][n] = e1 * rs; prob_s[2][n] = e2 * rs;
      prob_s[3][n] = e3 * rs; prob_s[4][n] = e4 * rs;
    }
    __syncthreads();
    // ---- PHASE C: L2 MFMA (+ xg prefetch p+1) | store p-1 ----
    if (p < P_ - 1) {
      const size_t pb = (size_t)((p + 1) * 256 + grp) * 3072;
#pragma unroll
      for (int i = 0; i < 3; ++i)
#pragma unroll
        for (int r = 0; r < 4; ++r)
          xp[i * 4 + r] = (lq < 2)
              ? xg2[pb + (size_t)((w * 3 + i) * 256 + r * 64 + (half * 2 + lq) * 16 + lj)]
              : (unsigned short)0;
    }
    f32x4 c2f[3];
#pragma unroll
    for (int i = 0; i < 3; ++i) {
      c2f[i][0] = bias2r[i]; c2f[i][1] = bias2r[i];
      c2f[i][2] = bias2r[i]; c2f[i][3] = bias2r[i];
    }
    {
      bf16x8 a0 = *(const bf16x8*)(hhrow + lq * 8);
      bf16x8 a1 = *(const bf16x8*)(hhrow + 32 + lq * 8);
      bf16x8 a2 = *(const bf16x8*)(hhrow + 64 + lq * 8);
      bf16x8 q0 = *(const bf16x8*)(hlrow + lq * 8);
      bf16x8 q1 = *(const bf16x8*)(hlrow + 32 + lq * 8);
      bf16x8 q2 = *(const bf16x8*)(hlrow + 64 + lq * 8);
#pragma unroll
      for (int i = 0; i < 3; ++i)
        c2f[i] = __builtin_amdgcn_mfma_f32_16x16x32_bf16(a0, b2f[i][0], c2f[i], 0, 0, 0);
#pragma unroll
      for (int i = 0; i < 3; ++i)
        c2f[i] = __builtin_amdgcn_mfma_f32_16x16x32_bf16(a1, b2f[i][1], c2f[i], 0, 0, 0);
#pragma unroll
      for (int i = 0; i < 3; ++i)
        c2f[i] = __builtin_amdgcn_mfma_f32_16x16x32_bf16(a2, b2f[i][2], c2f[i], 0, 0, 0);
#pragma unroll
      for (int i = 0; i < 3; ++i)
        c2f[i] = __builtin_amdgcn_mfma_f32_16x16x32_bf16(q0, b2f[i][0], c2f[i], 0, 0, 0);
#pragma unroll
      for (int i = 0; i < 3; ++i)
        c2f[i] = __builtin_amdgcn_mfma_f32_16x16x32_bf16(q1, b2f[i][1], c2f[i], 0, 0, 0);
#pragma unroll
      for (int i = 0; i < 3; ++i)
        c2f[i] = __builtin_amdgcn_mfma_f32_16x16x32_bf16(q2, b2f[i][2], c2f[i], 0, 0, 0);
    }
    if (lq < 2) {
#pragma unroll
      for (int i = 0; i < 3; ++i)
#pragma unroll
        for (int r = 0; r < 4; ++r)
          gs[lq * 4 + r][w * 48 + i * 16 + lj] = c2f[i][r];
    }
    if (p > 0 && tid >= 96 && tid < 136) {
      out[(((size_t)b * P_ + (p - 1)) * 5 + sk) * T_ + t0 + sn] = prob_s[sk][sn];
    }
    __syncthreads();
    // ---- PHASE D: L2 activations/h2 update ----
    {
      const int n = tn0, u = tu0;
      const float ig = gs[n][u], fg = gs[n][48 + u];
      const float gg = gs[n][96 + u], og = gs[n][144 + u];
      const float cc = sigf(fg) * c2r[0] + sigf(ig) * tanh_f(gg);
      c2r[0] = cc;
      const float h = sigf(og) * tanh_f(cc);
      const unsigned short hb = f2bs(h);
      hh[n][48 + u] = (short)hb;
      hl[n][48 + u] = (short)f2bs(h - bs2f(hb));
      h2f[n][u] = h;
    }
    if (tid < 128) {
      const int n = tn1, u = tu1;
      const float ig = gs[n][u], fg = gs[n][48 + u];
      const float gg = gs[n][96 + u], og = gs[n][144 + u];
      const float cc = sigf(fg) * c2r[1] + sigf(ig) * tanh_f(gg);
      c2r[1] = cc;
      const float h = sigf(og) * tanh_f(cc);
      const unsigned short hb = f2bs(h);
      hh[n][48 + u] = (short)hb;
      hl[n][48 + u] = (short)f2bs(h - bs2f(hb));
      h2f[n][u] = h;
    }
    __syncthreads();
  }
  // ---- epilogue: fc/softmax/store for p = P_-1 ----
  if (fcth) {
    float a = fcbr;
#pragma unroll
    for (int uq = 0; uq < 12; ++uq) {
      f32x4 hv = *(const f32x4*)&h2f[fn][uq * 4];
      f32x4 wv = *(const f32x4*)&fcws[fk * 48 + uq * 4];
      a += hv[0] * wv[0] + hv[1] * wv[1] + hv[2] * wv[2] + hv[3] * wv[3];
    }
    logit_s[fk][fn] = a;
  }
  __syncthreads();
  if (tid >= 192 && tid < 200) {
    const int n = tid - 192;
    const float l0 = logit_s[0][n], l1 = logit_s[1][n], l2 = logit_s[2][n],
                l3 = logit_s[3][n], l4 = logit_s[4][n];
    const float m = fmaxf(fmaxf(fmaxf(l0, l1), fmaxf(l2, l3)), l4);
    const float e0 = __expf(l0 - m), e1 = __expf(l1 - m), e2 = __expf(l2 - m),
                e3 = __expf(l3 - m), e4 = __expf(l4 - m);
    const float rs = __builtin_amdgcn_rcpf(e0 + e1 + e2 + e3 + e4);
    prob_s[0][n] = e0 * rs; prob_s[1][n] = e1 * rs; prob_s[2][n] = e2 * rs;
    prob_s[3][n] = e3 * rs; prob_s[4][n] = e4 * rs;
  }
  __syncthreads();
  if (tid >= 96 && tid < 136) {
    out[(((size_t)b * P_ + (P_ - 1)) * 5 + sk) * T_ + t0 + sn] = prob_s[sk][sn];
  }
}

extern "C" void kernel_launch(void* const* d_in, const int* in_sizes, int n_in,
                              void* d_out, int out_size, void* d_ws, size_t ws_size,
                              hipStream_t stream) {
  const float* pf   = (const float*)d_in[0];
  const float* pc   = (const float*)d_in[1];
  const float* fc1w = (const float*)d_in[2];
  const float* fc1b = (const float*)d_in[3];
  const float* fc2w = (const float*)d_in[4];
  const float* fc2b = (const float*)d_in[5];
  const float* fc3w = (const float*)d_in[6];
  const float* fc3b = (const float*)d_in[7];
  const float* wih1 = (const float*)d_in[8];
  const float* whh1 = (const float*)d_in[9];
  const float* bih1 = (const float*)d_in[10];
  const float* bhh1 = (const float*)d_in[11];
  const float* wih2 = (const float*)d_in[12];
  const float* whh2 = (const float*)d_in[13];
  const float* bih2 = (const float*)d_in[14];
  const float* bhh2 = (const float*)d_in[15];
  const float* fcw  = (const float*)d_in[16];
  const float* fcb  = (const float*)d_in[17];
  float* out = (float*)d_out;

  char* wsp = (char*)d_ws;
  float* ctxg = (float*)wsp;                                     // 1,081,344 B
  const size_t CTXG_BYTES = (size_t)B_ * P_ * G_ * sizeof(float);
  f16x8* wfrag = (f16x8*)(wsp + CTXG_BYTES);                     // 73,728 B
  const size_t WFRAG_BYTES = (size_t)12 * 6 * 64 * 16;
  unsigned short* xg2 = (unsigned short*)(wsp + CTXG_BYTES + WFRAG_BYTES);  // ~138.5 MB

  ctx_kernel<<<22, 64, 0, stream>>>(pc, fc1w, fc1b, fc2w, fc2b, fc3w, fc3b,
                                    wih1, bih1, bhh1, ctxg);
  wfrag_kernel<<<18, 256, 0, stream>>>(wih1, wfrag);
  gemm_mfma<<<B_ * P_ * 2, 256, 0, stream>>>(pf, wfrag, ctxg, xg2);
  scan_mfma<<<N_ / 8, 256, 0, stream>>>(xg2, whh1, wih2, whh2,
                                        bih2, bhh2, fcw, fcb, out);
}

// Round 10
// 413.247 us; speedup vs baseline: 1.0315x; 1.0315x over previous
//
#include <hip/hip_runtime.h>
#include <hip/hip_bf16.h>
#include <cstdint>

#define P_ 88   // pitches (sequence length of the scan)
#define B_ 16   // batch
#define T_ 256  // timesteps (folded into batch N)
#define H_ 188  // per-pitch features
#define G_ 192  // 4*48 gates; also LSTM1 input size (188 feat + 4 ctx)
#define U_ 48   // LSTM units
#define N_ 4096 // B_*T_

typedef __attribute__((ext_vector_type(8))) short bf16x8;
typedef __attribute__((ext_vector_type(8))) _Float16 f16x8;
typedef __attribute__((ext_vector_type(4))) float f32x4;

__device__ __forceinline__ float sigf(float x) {
  return __builtin_amdgcn_rcpf(1.0f + __expf(-x));
}
__device__ __forceinline__ float tanh_f(float x) {
  return 1.0f - 2.0f * __builtin_amdgcn_rcpf(1.0f + __expf(2.0f * x));
}
__device__ __forceinline__ unsigned short f2bs(float v) {
  union { __hip_bfloat16 h; unsigned short s; } u;
  u.h = __float2bfloat16(v);
  return u.s;
}
__device__ __forceinline__ float bs2f(unsigned short s) {
  union { unsigned int u; float f; } x;
  x.u = ((unsigned int)s) << 16;
  return x.f;
}
__device__ __forceinline__ float hs2f(unsigned short s) {
  union { unsigned short u; _Float16 h; } x;
  x.u = s;
  return (float)x.h;
}
__device__ __forceinline__ unsigned short f2hs(float v) {
  union { _Float16 h; unsigned short s; } x;
  x.h = (_Float16)v;
  return x.s;
}

// Relaxed workgroup barrier: waits only on LDS ops (lgkmcnt), NOT on
// outstanding global loads/stores (vmcnt). __syncthreads() would emit a
// full vmcnt(0) drain, exposing the xp prefetch's HBM latency every phase.
// Safe here: no cross-thread communication through global memory in-loop.
__device__ __forceinline__ void lds_barrier() {
  asm volatile("s_waitcnt lgkmcnt(0)\n\ts_barrier" ::: "memory");
}

// ---------------------------------------------------------------------------
// Kernel 1: context MLP -> per-(b,p) gate bias vector
// ---------------------------------------------------------------------------
__global__ void ctx_kernel(const float* __restrict__ pc,
                           const float* __restrict__ fc1w, const float* __restrict__ fc1b,
                           const float* __restrict__ fc2w, const float* __restrict__ fc2b,
                           const float* __restrict__ fc3w, const float* __restrict__ fc3b,
                           const float* __restrict__ wih1,
                           const float* __restrict__ bih1, const float* __restrict__ bhh1,
                           float* __restrict__ ctxg) {
  int bp = blockIdx.x * 64 + threadIdx.x;
  if (bp >= B_ * P_) return;
  float p0 = pc[bp * 3 + 0], p1 = pc[bp * 3 + 1], p2 = pc[bp * 3 + 2];
  float x1[16], x2[16];
#pragma unroll
  for (int jj = 0; jj < 16; ++jj)
    x1[jj] = fmaxf(0.f, fc1w[jj * 3 + 0] * p0 + fc1w[jj * 3 + 1] * p1 + fc1w[jj * 3 + 2] * p2 + fc1b[jj]);
#pragma unroll
  for (int jj = 0; jj < 16; ++jj) {
    float s = fc2b[jj];
#pragma unroll
    for (int i = 0; i < 16; ++i) s += fc2w[jj * 16 + i] * x1[i];
    x2[jj] = fmaxf(0.f, s);
  }
  float ce[4];
#pragma unroll
  for (int jj = 0; jj < 4; ++jj) {
    float s = fc3b[jj];
#pragma unroll
    for (int i = 0; i < 16; ++i) s += fc3w[jj * 16 + i] * x2[i];
    ce[jj] = s;
  }
  float* op = ctxg + (size_t)bp * G_;
  for (int g = 0; g < G_; ++g) {
    const float* wr = wih1 + (size_t)g * G_ + H_;
    op[g] = bih1[g] + bhh1[g] + ce[0] * wr[0] + ce[1] * wr[1] + ce[2] * wr[2] + ce[3] * wr[3];
  }
}

// ---------------------------------------------------------------------------
// Kernel 1b: pack wih1 feature columns (k<188, pad to 192) into f16 MFMA
// B-fragment order: wfrag[(j*6+kc)*64 + l] (74 KB, L2-hot for all blocks).
// ---------------------------------------------------------------------------
__global__ __launch_bounds__(256) void wfrag_kernel(const float* __restrict__ wih1,
                                                    f16x8* __restrict__ wfrag) {
  const int idx = blockIdx.x * 256 + threadIdx.x;
  if (idx >= 12 * 6 * 64) return;
  const int l = idx & 63;
  const int kc = (idx >> 6) % 6;
  const int j = idx / 384;
  const int g = j * 16 + (l & 15);
  const int k0 = kc * 32 + (l >> 4) * 8;
  f16x8 v;
#pragma unroll
  for (int e = 0; e < 8; ++e) {
    const int k = k0 + e;
    const float wv = (k < H_) ? wih1[(size_t)g * G_ + k] : 0.f;
    v[e] = (_Float16)wv;
  }
  wfrag[idx] = v;
}

// ---------------------------------------------------------------------------
// Kernel 2: MFMA GEMM with LDS-staged A and LDS-repacked stores (unchanged).
// ---------------------------------------------------------------------------
__global__ __launch_bounds__(256, 3) void gemm_mfma(const float* __restrict__ pf,
                                                    const f16x8* __restrict__ wfrag,
                                                    const float* __restrict__ ctxg,
                                                    unsigned short* __restrict__ xg2) {
  const int bp = blockIdx.x >> 1, tb = blockIdx.x & 1;
  const int p = bp % P_, b = bp / P_;
  const int tid = threadIdx.x;
  const int w = tid >> 6, l = tid & 63;
  const int lj = l & 15, lq = l >> 4;

  __shared__ __align__(16) char ldsraw[49152];  // 48 KB: staging then epilogue
  _Float16(*Ahi)[34] = (_Float16(*)[34])ldsraw;             // [128][34] f16
  _Float16(*Alo)[34] = (_Float16(*)[34])(ldsraw + 8704);    // [128][34] f16

  float cg[12];
#pragma unroll
  for (int jn = 0; jn < 12; ++jn)
    cg[jn] = ctxg[(size_t)bp * G_ + jn * 16 + lj];

  f32x4 acc[2][12];
#pragma unroll
  for (int mt = 0; mt < 2; ++mt)
#pragma unroll
    for (int jn = 0; jn < 12; ++jn)
#pragma unroll
      for (int r = 0; r < 4; ++r) acc[mt][jn][r] = 0.f;

  const float* Ab = pf + (size_t)bp * H_ * T_ + tb * 128;
  const int kl = tid >> 5;         // 0..7  (k row within an 8-row group)
  const int t4 = (tid & 31) * 4;   // 0..124 (t within the 128-half)

  for (int kc = 0; kc < 6; ++kc) {
    __syncthreads();  // previous chunk's fragment reads complete
#pragma unroll
    for (int rr = 0; rr < 4; ++rr) {
      const int kk = rr * 8 + kl;       // 0..31 within chunk
      const int kg = kc * 32 + kk;
      float a0 = 0.f, a1 = 0.f, a2 = 0.f, a3 = 0.f;
      if (kg < H_) {
        const float4 v = *(const float4*)(Ab + (size_t)kg * T_ + t4);
        a0 = v.x; a1 = v.y; a2 = v.z; a3 = v.w;
      }
      const _Float16 h0 = (_Float16)a0, h1 = (_Float16)a1;
      const _Float16 h2 = (_Float16)a2, h3 = (_Float16)a3;
      Ahi[t4 + 0][kk] = h0; Alo[t4 + 0][kk] = (_Float16)(a0 - (float)h0);
      Ahi[t4 + 1][kk] = h1; Alo[t4 + 1][kk] = (_Float16)(a1 - (float)h1);
      Ahi[t4 + 2][kk] = h2; Alo[t4 + 2][kk] = (_Float16)(a2 - (float)h2);
      Ahi[t4 + 3][kk] = h3; Alo[t4 + 3][kk] = (_Float16)(a3 - (float)h3);
    }
    __syncthreads();
    const int trow = w * 32;
    const f16x8 ahi0 = *(const f16x8*)&Ahi[trow + lj][lq * 8];
    const f16x8 ahi1 = *(const f16x8*)&Ahi[trow + 16 + lj][lq * 8];
    const f16x8 alo0 = *(const f16x8*)&Alo[trow + lj][lq * 8];
    const f16x8 alo1 = *(const f16x8*)&Alo[trow + 16 + lj][lq * 8];
#pragma unroll
    for (int jn = 0; jn < 12; ++jn) {
      const f16x8 wf = wfrag[(jn * 6 + kc) * 64 + l];
      acc[0][jn] = __builtin_amdgcn_mfma_f32_16x16x32_f16(ahi0, wf, acc[0][jn], 0, 0, 0);
      acc[1][jn] = __builtin_amdgcn_mfma_f32_16x16x32_f16(ahi1, wf, acc[1][jn], 0, 0, 0);
      acc[0][jn] = __builtin_amdgcn_mfma_f32_16x16x32_f16(alo0, wf, acc[0][jn], 0, 0, 0);
      acc[1][jn] = __builtin_amdgcn_mfma_f32_16x16x32_f16(alo1, wf, acc[1][jn], 0, 0, 0);
    }
  }
  __syncthreads();  // staging region now free for epilogue reuse

  // ---- epilogue: + ctx bias, f16, repack via per-wave LDS, uint4 stores ----
  unsigned short* Cst = (unsigned short*)ldsraw + w * 6144;  // 12 KB per wave
#pragma unroll
  for (int mt = 0; mt < 2; ++mt)
#pragma unroll
    for (int jn = 0; jn < 12; ++jn)
#pragma unroll
      for (int r = 0; r < 4; ++r)
        Cst[mt * 3072 + jn * 256 + r * 64 + l] = f2hs(acc[mt][jn][r] + cg[jn]);
  const int nb0 = b * 16 + tb * 8 + w * 2;
  unsigned short* gb = xg2 + ((size_t)p * 256 + nb0) * 3072;
#pragma unroll
  for (int rr = 0; rr < 12; ++rr) {
    const uint4 v = *(const uint4*)(Cst + rr * 512 + l * 8);
    *(uint4*)(gb + rr * 512 + l * 8) = v;
  }
}

// ---------------------------------------------------------------------------
// Kernel 3: MFMA persistent scan. NB=8, 512 blocks = 2 blocks/CU.
// Round-9 changes: (1) relaxed lds_barrier (no vmcnt drain in-loop) so xp
// prefetch latency hides across phases; (2) prefetch issued at top of phase A
// (max in-flight distance); (3) MFMA accumulate chains split in half.
// ---------------------------------------------------------------------------
__global__ __launch_bounds__(256, 2) void scan_mfma(
    const unsigned short* __restrict__ xg2,
    const float* __restrict__ whh1, const float* __restrict__ wih2,
    const float* __restrict__ whh2, const float* __restrict__ bih2,
    const float* __restrict__ bhh2, const float* __restrict__ fcw,
    const float* __restrict__ fcb, float* __restrict__ out) {
  __shared__ __align__(16) short hh[16][104];   // h hi bits: cols 0-47 h1, 48-95 h2 (rows 8-15 stay 0)
  __shared__ __align__(16) short hl[16][104];   // h lo bits
  __shared__ __align__(16) float gs[8][196];    // gate staging (one layer at a time)
  __shared__ __align__(16) float h2f[8][52];    // h2 fp32 for fc_states
  __shared__ __align__(16) float fcws[5 * 48];
  __shared__ float logit_s[5][8];
  __shared__ float prob_s[5][8];

  const int tid = threadIdx.x;
  const int w = tid >> 6;   // wave 0..3
  const int l = tid & 63;
  const int lj = l & 15;    // A-row m / C col n within a 16-tile
  const int lq = l >> 4;    // quad
  const int grp = blockIdx.x >> 1;   // 16-row group in xg2
  const int half = blockIdx.x & 1;   // which 8-row half
  const int n0 = blockIdx.x * 8;
  const int b = n0 >> 8, t0 = n0 & 255;

  // ---- persistent weight B-fragments (one-time gather) ----
  bf16x8 b1[3][2];
  bf16x8 b2f[3][3];
  float bias2r[3];
#pragma unroll
  for (int i = 0; i < 3; ++i) {
    const int j = w * 48 + i * 16 + lj;
    bias2r[i] = bih2[j] + bhh2[j];
#pragma unroll
    for (int kc = 0; kc < 2; ++kc)
#pragma unroll
      for (int e = 0; e < 8; ++e) {
        const int u = kc * 32 + lq * 8 + e;
        b1[i][kc][e] = (u < U_) ? (short)f2bs(whh1[j * U_ + u]) : (short)0;
      }
#pragma unroll
    for (int kc = 0; kc < 3; ++kc)
#pragma unroll
      for (int e = 0; e < 8; ++e) {
        const int u = kc * 32 + lq * 8 + e;
        b2f[i][kc][e] = (u < U_) ? (short)f2bs(wih2[j * U_ + u])
                                 : (short)f2bs(whh2[j * U_ + (u - U_)]);
      }
  }

  for (int e = tid; e < 16 * 104 / 2; e += 256) {
    ((unsigned int*)hh)[e] = 0u;
    ((unsigned int*)hl)[e] = 0u;
  }
  for (int e = tid; e < 5 * U_; e += 256) fcws[e] = fcw[e];

  // activation tasks: 8 rows x 48 units = 384 per layer; slot 0 = tid,
  // slot 1 = 256+tid (valid for tid<128)
  const int tn0 = tid / U_, tu0 = tid % U_;
  const int tn1 = (256 + tid) / U_, tu1 = (256 + tid) % U_;
  float c1r[2] = {0.f, 0.f}, c2r[2] = {0.f, 0.f};
  // fc-logit threads (0..39), softmax threads (192..199), store threads (96..135)
  const bool fcth = tid < 40;
  const int fk = tid >> 3, fn = tid & 7;
  const float fcbr = fcth ? fcb[fk] : 0.f;
  const int sk = (tid - 96) >> 3, sn = (tid - 96) & 7;

  // xg prefetch for p=0 (lanes lq<2 hold rows half*8 + lq*4+r)
  unsigned short xp[12];
  {
    const size_t pb = (size_t)grp * 3072;
#pragma unroll
    for (int i = 0; i < 3; ++i)
#pragma unroll
      for (int r = 0; r < 4; ++r)
        xp[i * 4 + r] = (lq < 2)
            ? xg2[pb + (size_t)((w * 3 + i) * 256 + r * 64 + (half * 2 + lq) * 16 + lj)]
            : (unsigned short)0;
  }
  const short* hhrow = &hh[lj][0];
  const short* hlrow = &hl[lj][0];
  lds_barrier();

  for (int p = 0; p < P_; ++p) {
    // ---- PHASE A: L1 MFMA (C init = xg) + issue p+1 prefetch | fc logits ----
    f32x4 cH[3], cL[3];
#pragma unroll
    for (int i = 0; i < 3; ++i)
#pragma unroll
      for (int r = 0; r < 4; ++r) { cH[i][r] = hs2f(xp[i * 4 + r]); cL[i][r] = 0.f; }
    if (p < P_ - 1) {  // issue next-step loads NOW; they stay in flight across
                       // the relaxed barriers until consumed next phase A
      const size_t pb = (size_t)((p + 1) * 256 + grp) * 3072;
#pragma unroll
      for (int i = 0; i < 3; ++i)
#pragma unroll
        for (int r = 0; r < 4; ++r)
          xp[i * 4 + r] = (lq < 2)
              ? xg2[pb + (size_t)((w * 3 + i) * 256 + r * 64 + (half * 2 + lq) * 16 + lj)]
              : (unsigned short)0;
    }
    {
      bf16x8 ah0 = *(const bf16x8*)(hhrow + lq * 8);
      bf16x8 ah1 = *(const bf16x8*)(hhrow + 32 + lq * 8);
      bf16x8 al0 = *(const bf16x8*)(hlrow + lq * 8);
      bf16x8 al1 = *(const bf16x8*)(hlrow + 32 + lq * 8);
      // two independent 2-deep chains per tile (round-8 was one 4-deep chain)
#pragma unroll
      for (int i = 0; i < 3; ++i)
        cH[i] = __builtin_amdgcn_mfma_f32_16x16x32_bf16(ah0, b1[i][0], cH[i], 0, 0, 0);
#pragma unroll
      for (int i = 0; i < 3; ++i)
        cL[i] = __builtin_amdgcn_mfma_f32_16x16x32_bf16(al0, b1[i][0], cL[i], 0, 0, 0);
#pragma unroll
      for (int i = 0; i < 3; ++i)
        cH[i] = __builtin_amdgcn_mfma_f32_16x16x32_bf16(ah1, b1[i][1], cH[i], 0, 0, 0);
#pragma unroll
      for (int i = 0; i < 3; ++i)
        cL[i] = __builtin_amdgcn_mfma_f32_16x16x32_bf16(al1, b1[i][1], cL[i], 0, 0, 0);
    }
    if (lq < 2) {
#pragma unroll
      for (int i = 0; i < 3; ++i)
#pragma unroll
        for (int r = 0; r < 4; ++r)
          gs[lq * 4 + r][w * 48 + i * 16 + lj] = cH[i][r] + cL[i][r];
    }
    if (p > 0 && fcth) {
      float a = fcbr;
#pragma unroll
      for (int uq = 0; uq < 12; ++uq) {
        f32x4 hv = *(const f32x4*)&h2f[fn][uq * 4];
        f32x4 wv = *(const f32x4*)&fcws[fk * 48 + uq * 4];
        a += hv[0] * wv[0] + hv[1] * wv[1] + hv[2] * wv[2] + hv[3] * wv[3];
      }
      logit_s[fk][fn] = a;
    }
    lds_barrier();
    // ---- PHASE B: L1 activations/h1 update | softmax for p-1 ----
    {
      const int n = tn0, u = tu0;
      const float ig = gs[n][u], fg = gs[n][48 + u];
      const float gg = gs[n][96 + u], og = gs[n][144 + u];
      const float cc = sigf(fg) * c1r[0] + sigf(ig) * tanh_f(gg);
      c1r[0] = cc;
      const float h = sigf(og) * tanh_f(cc);
      const unsigned short hb = f2bs(h);
      hh[n][u] = (short)hb;
      hl[n][u] = (short)f2bs(h - bs2f(hb));
    }
    if (tid < 128) {
      const int n = tn1, u = tu1;
      const float ig = gs[n][u], fg = gs[n][48 + u];
      const float gg = gs[n][96 + u], og = gs[n][144 + u];
      const float cc = sigf(fg) * c1r[1] + sigf(ig) * tanh_f(gg);
      c1r[1] = cc;
      const float h = sigf(og) * tanh_f(cc);
      const unsigned short hb = f2bs(h);
      hh[n][u] = (short)hb;
      hl[n][u] = (short)f2bs(h - bs2f(hb));
    }
    if (p > 0 && tid >= 192 && tid < 200) {
      const int n = tid - 192;
      const float l0 = logit_s[0][n], l1 = logit_s[1][n], l2 = logit_s[2][n],
                  l3 = logit_s[3][n], l4 = logit_s[4][n];
      const float m = fmaxf(fmaxf(fmaxf(l0, l1), fmaxf(l2, l3)), l4);
      const float e0 = __expf(l0 - m), e1 = __expf(l1 - m), e2 = __expf(l2 - m),
                  e3 = __expf(l3 - m), e4 = __expf(l4 - m);
      const float rs = __builtin_amdgcn_rcpf(e0 + e1 + e2 + e3 + e4);
      prob_s[0][n] = e0 * rs; prob_s[1][n] = e1 * rs; prob_s[2][n] = e2 * rs;
      prob_s[3][n] = e3 * rs; prob_s[4][n] = e4 * rs;
    }
    lds_barrier();
    // ---- PHASE C: L2 MFMA | store p-1 ----
    f32x4 c2H[3], c2L[3];
#pragma unroll
    for (int i = 0; i < 3; ++i) {
      c2H[i][0] = bias2r[i]; c2H[i][1] = bias2r[i];
      c2H[i][2] = bias2r[i]; c2H[i][3] = bias2r[i];
      c2L[i][0] = 0.f; c2L[i][1] = 0.f; c2L[i][2] = 0.f; c2L[i][3] = 0.f;
    }
    {
      bf16x8 a0 = *(const bf16x8*)(hhrow + lq * 8);
      bf16x8 a1 = *(const bf16x8*)(hhrow + 32 + lq * 8);
      bf16x8 a2 = *(const bf16x8*)(hhrow + 64 + lq * 8);
      bf16x8 q0 = *(const bf16x8*)(hlrow + lq * 8);
      bf16x8 q1 = *(const bf16x8*)(hlrow + 32 + lq * 8);
      bf16x8 q2 = *(const bf16x8*)(hlrow + 64 + lq * 8);
#pragma unroll
      for (int i = 0; i < 3; ++i)
        c2H[i] = __builtin_amdgcn_mfma_f32_16x16x32_bf16(a0, b2f[i][0], c2H[i], 0, 0, 0);
#pragma unroll
      for (int i = 0; i < 3; ++i)
        c2L[i] = __builtin_amdgcn_mfma_f32_16x16x32_bf16(q0, b2f[i][0], c2L[i], 0, 0, 0);
#pragma unroll
      for (int i = 0; i < 3; ++i)
        c2H[i] = __builtin_amdgcn_mfma_f32_16x16x32_bf16(a1, b2f[i][1], c2H[i], 0, 0, 0);
#pragma unroll
      for (int i = 0; i < 3; ++i)
        c2L[i] = __builtin_amdgcn_mfma_f32_16x16x32_bf16(q1, b2f[i][1], c2L[i], 0, 0, 0);
#pragma unroll
      for (int i = 0; i < 3; ++i)
        c2H[i] = __builtin_amdgcn_mfma_f32_16x16x32_bf16(a2, b2f[i][2], c2H[i], 0, 0, 0);
#pragma unroll
      for (int i = 0; i < 3; ++i)
        c2L[i] = __builtin_amdgcn_mfma_f32_16x16x32_bf16(q2, b2f[i][2], c2L[i], 0, 0, 0);
    }
    if (lq < 2) {
#pragma unroll
      for (int i = 0; i < 3; ++i)
#pragma unroll
        for (int r = 0; r < 4; ++r)
          gs[lq * 4 + r][w * 48 + i * 16 + lj] = c2H[i][r] + c2L[i][r];
    }
    if (p > 0 && tid >= 96 && tid < 136) {
      out[(((size_t)b * P_ + (p - 1)) * 5 + sk) * T_ + t0 + sn] = prob_s[sk][sn];
    }
    lds_barrier();
    // ---- PHASE D: L2 activations/h2 update ----
    {
      const int n = tn0, u = tu0;
      const float ig = gs[n][u], fg = gs[n][48 + u];
      const float gg = gs[n][96 + u], og = gs[n][144 + u];
      const float cc = sigf(fg) * c2r[0] + sigf(ig) * tanh_f(gg);
      c2r[0] = cc;
      const float h = sigf(og) * tanh_f(cc);
      const unsigned short hb = f2bs(h);
      hh[n][48 + u] = (short)hb;
      hl[n][48 + u] = (short)f2bs(h - bs2f(hb));
      h2f[n][u] = h;
    }
    if (tid < 128) {
      const int n = tn1, u = tu1;
      const float ig = gs[n][u], fg = gs[n][48 + u];
      const float gg = gs[n][96 + u], og = gs[n][144 + u];
      const float cc = sigf(fg) * c2r[1] + sigf(ig) * tanh_f(gg);
      c2r[1] = cc;
      const float h = sigf(og) * tanh_f(cc);
      const unsigned short hb = f2bs(h);
      hh[n][48 + u] = (short)hb;
      hl[n][48 + u] = (short)f2bs(h - bs2f(hb));
      h2f[n][u] = h;
    }
    lds_barrier();
  }
  // ---- epilogue: fc/softmax/store for p = P_-1 ----
  if (fcth) {
    float a = fcbr;
#pragma unroll
    for (int uq = 0; uq < 12; ++uq) {
      f32x4 hv = *(const f32x4*)&h2f[fn][uq * 4];
      f32x4 wv = *(const f32x4*)&fcws[fk * 48 + uq * 4];
      a += hv[0] * wv[0] + hv[1] * wv[1] + hv[2] * wv[2] + hv[3] * wv[3];
    }
    logit_s[fk][fn] = a;
  }
  lds_barrier();
  if (tid >= 192 && tid < 200) {
    const int n = tid - 192;
    const float l0 = logit_s[0][n], l1 = logit_s[1][n], l2 = logit_s[2][n],
                l3 = logit_s[3][n], l4 = logit_s[4][n];
    const float m = fmaxf(fmaxf(fmaxf(l0, l1), fmaxf(l2, l3)), l4);
    const float e0 = __expf(l0 - m), e1 = __expf(l1 - m), e2 = __expf(l2 - m),
                e3 = __expf(l3 - m), e4 = __expf(l4 - m);
    const float rs = __builtin_amdgcn_rcpf(e0 + e1 + e2 + e3 + e4);
    prob_s[0][n] = e0 * rs; prob_s[1][n] = e1 * rs; prob_s[2][n] = e2 * rs;
    prob_s[3][n] = e3 * rs; prob_s[4][n] = e4 * rs;
  }
  lds_barrier();
  if (tid >= 96 && tid < 136) {
    out[(((size_t)b * P_ + (P_ - 1)) * 5 + sk) * T_ + t0 + sn] = prob_s[sk][sn];
  }
}

extern "C" void kernel_launch(void* const* d_in, const int* in_sizes, int n_in,
                              void* d_out, int out_size, void* d_ws, size_t ws_size,
                              hipStream_t stream) {
  const float* pf   = (const float*)d_in[0];
  const float* pc   = (const float*)d_in[1];
  const float* fc1w = (const float*)d_in[2];
  const float* fc1b = (const float*)d_in[3];
  const float* fc2w = (const float*)d_in[4];
  const float* fc2b = (const float*)d_in[5];
  const float* fc3w = (const float*)d_in[6];
  const float* fc3b = (const float*)d_in[7];
  const float* wih1 = (const float*)d_in[8];
  const float* whh1 = (const float*)d_in[9];
  const float* bih1 = (const float*)d_in[10];
  const float* bhh1 = (const float*)d_in[11];
  const float* wih2 = (const float*)d_in[12];
  const float* whh2 = (const float*)d_in[13];
  const float* bih2 = (const float*)d_in[14];
  const float* bhh2 = (const float*)d_in[15];
  const float* fcw  = (const float*)d_in[16];
  const float* fcb  = (const float*)d_in[17];
  float* out = (float*)d_out;

  char* wsp = (char*)d_ws;
  float* ctxg = (float*)wsp;                                     // 1,081,344 B
  const size_t CTXG_BYTES = (size_t)B_ * P_ * G_ * sizeof(float);
  f16x8* wfrag = (f16x8*)(wsp + CTXG_BYTES);                     // 73,728 B
  const size_t WFRAG_BYTES = (size_t)12 * 6 * 64 * 16;
  unsigned short* xg2 = (unsigned short*)(wsp + CTXG_BYTES + WFRAG_BYTES);  // ~138.5 MB

  ctx_kernel<<<22, 64, 0, stream>>>(pc, fc1w, fc1b, fc2w, fc2b, fc3w, fc3b,
                                    wih1, bih1, bhh1, ctxg);
  wfrag_kernel<<<18, 256, 0, stream>>>(wih1, wfrag);
  gemm_mfma<<<B_ * P_ * 2, 256, 0, stream>>>(pf, wfrag, ctxg, xg2);
  scan_mfma<<<N_ / 8, 256, 0, stream>>>(xg2, whh1, wih2, whh2,
                                        bih2, bhh2, fcw, fcb, out);
}